// Round 11
// baseline (39.048 us; speedup 1.0000x reference)
//
#include <hip/hip_runtime.h>

#define W 512
#define H 512
#define CH_PIX (W * H)

// Block: one channel x 4 row-strips (grid 96 x 8; 4 waves/block).
// Wave owns a FULL 512-px-wide strip of 16 rows; lane owns 8 contiguous px
// (2 x float4). No half-row seam: the only horizontal edges are the true
// image edges (lane 0 / lane 63), handled by 2 shuffles + 2 selects per row.
// This removes the former per-half-row gather/readlane seam machinery and
// halves wave count: 3072 waves -> 3 waves/SIMD for FULL one-round residency,
// robust to VGPR up to 170 (the R6/R9 cap trap is structurally gone).
// Two bursts (rows 0..8, then 9..16) of 2xfloat4 row loads keep ~16KB/wave
// of VMEM in flight. NO second __launch_bounds__ arg (R6/R9: cap < natural
// pressure => scratch spill catastrophe).
// Bottom strip (rows 496..511): row 16 is all zeros -- bit-identical to the
// reference's zero padding.
// bin = LBP code >> 5 (== floor(code*8/255)): only bits 5..7 matter:
// s (down), nb5 (down-left bilinear), nb7 (down-right bilinear).
// Per-thread 8x8-bit packed counters in one u64 (max 128/bin), merged once.
__global__ __launch_bounds__(256) void lbp_main_k(const float* __restrict__ x,
                                                  unsigned int* __restrict__ ws) {
    const int chan = blockIdx.x;      // 0..95
    const int bg   = blockIdx.y;      // 0..7
    const int tid  = threadIdx.x;
    const int wave = tid >> 6;
    const int lane = tid & 63;
    const int strip = bg * 4 + wave;  // 0..31
    const int y0 = strip * 16;
    const bool lastStrip = (strip == 31);

    __shared__ unsigned int h[8 * 64];
    for (int i = tid; i < 512; i += 256) h[i] = 0u;
    __syncthreads();

    constexpr double Sd = 0.7071067811865476;
    constexpr double Td = 1.0 - Sd;
    const float wSS = (float)(Sd * Sd);
    const float wST = (float)(Sd * Td);
    const float wTT = (float)(Td * Td);

    const float* rp = x + chan * CH_PIX + y0 * W + (lane << 3);
    const bool l0 = (lane == 0), l63 = (lane == 63);

    unsigned long long c64 = 0ull;

    // ---- burst A: rows 0..8 (18 x dwordx4 per lane in flight) ----
    float4 bufA[9], bufB[9];
    #pragma unroll
    for (int k = 0; k < 9; ++k) {
        bufA[k] = *(const float4*)(rp + k * W);
        bufB[k] = *(const float4*)(rp + k * W + 4);
    }

    auto grp = [&](const float c_[4], const float e_[4], const float w_[4],
                   const float s_[4], const float sw_[4], const float se_[4]) {
        #pragma unroll
        for (int i = 0; i < 4; ++i) {
            const float c  = c_[i];
            const float tc = wTT * c;
            const float ts = wST * s_[i];
            const float nb5 = ((wST * w_[i] + tc) + wSS * sw_[i]) + ts;
            const float nb7 = ((tc + wST * e_[i]) + ts) + wSS * se_[i];
            const bool p0 = (nb5   >= c);
            const bool p1 = (s_[i] >= c);
            const bool p2 = (nb7   >= c);
            unsigned int t = p0 ? 0x100u : 1u;     // 1 << (8*p0)
            t = p1 ? (t << 16) : t;                // << 16*p1
            c64 += (unsigned long long)t << (p2 ? 32 : 0);
        }
    };

    auto rowstep = [&](const float4& ma, const float4& mb, float mL, float mR,
                       const float4& da, const float4& db, float dL, float dR) {
        {   // px 0..3
            const float cs[4]  = {ma.x, ma.y, ma.z, ma.w};
            const float es[4]  = {ma.y, ma.z, ma.w, mb.x};
            const float wsA[4] = {mL,   ma.x, ma.y, ma.z};
            const float ss[4]  = {da.x, da.y, da.z, da.w};
            const float sws[4] = {dL,   da.x, da.y, da.z};
            const float ses[4] = {da.y, da.z, da.w, db.x};
            grp(cs, es, wsA, ss, sws, ses);
        }
        {   // px 4..7
            const float cs[4]  = {mb.x, mb.y, mb.z, mb.w};
            const float es[4]  = {mb.y, mb.z, mb.w, mR};
            const float wsA[4] = {ma.w, mb.x, mb.y, mb.z};
            const float ss[4]  = {db.x, db.y, db.z, db.w};
            const float sws[4] = {da.w, db.x, db.y, db.z};
            const float ses[4] = {db.y, db.z, db.w, dR};
            grp(cs, es, wsA, ss, sws, ses);
        }
    };

    auto edges = [&](const float4& a, const float4& b) -> float2 {
        const float up = __shfl_up(b.w, 1, 64);    // lane-1 px7 -> left of px0
        const float dn = __shfl_down(a.x, 1, 64);  // lane+1 px0 -> right of px7
        float2 r;
        r.x = l0  ? 0.0f : up;
        r.y = l63 ? 0.0f : dn;
        return r;
    };

    // ---- phase A compute: rows 0..7 ----
    float4 ma = bufA[0], mb = bufB[0];
    float2 mlr = edges(ma, mb);
    #pragma unroll
    for (int k = 0; k < 8; ++k) {
        const float4 da = bufA[k + 1], db = bufB[k + 1];
        const float2 dlr = edges(da, db);
        rowstep(ma, mb, mlr.x, mlr.y, da, db, dlr.x, dlr.y);
        ma = da; mb = db; mlr = dlr;
    }

    // ---- burst B: rows 9..16 into slots 0..7 (row 16 = zeros on last strip) ----
    #pragma unroll
    for (int k = 0; k < 8; ++k) {
        if (k == 7 && lastStrip) {
            bufA[k] = make_float4(0.0f, 0.0f, 0.0f, 0.0f);
            bufB[k] = make_float4(0.0f, 0.0f, 0.0f, 0.0f);
        } else {
            bufA[k] = *(const float4*)(rp + (9 + k) * W);
            bufB[k] = *(const float4*)(rp + (9 + k) * W + 4);
        }
    }

    // ---- phase B compute: rows 8..15 (ma/mb carry row 8 from phase A) ----
    #pragma unroll
    for (int k = 0; k < 8; ++k) {
        const float4 da = bufA[k], db = bufB[k];
        const float2 dlr = edges(da, db);
        rowstep(ma, mb, mlr.x, mlr.y, da, db, dlr.x, dlr.y);
        ma = da; mb = db; mlr = dlr;
    }

    // merge packed byte counters into LDS histogram (8 DS atomics/thread;
    // h[bin*64+lane]: 2 lanes/bank within a wave = conflict-free)
    const unsigned int lo = (unsigned int)c64;
    const unsigned int hi = (unsigned int)(c64 >> 32);
    #pragma unroll
    for (int b = 0; b < 4; ++b) {
        atomicAdd(&h[(b       << 6) + lane], (lo >> (b * 8)) & 0xffu);
        atomicAdd(&h[((b + 4) << 6) + lane], (hi >> (b * 8)) & 0xffu);
    }
    __syncthreads();

    // block tail: wave w reduces bins w and w+4 via shfl_xor tree
    unsigned int v0 = h[tid];          // bin = wave,   copy = lane
    unsigned int v1 = h[tid + 256];    // bin = wave+4, copy = lane
    #pragma unroll
    for (int o = 32; o >= 1; o >>= 1) {
        v0 += __shfl_xor(v0, o, 64);
        v1 += __shfl_xor(v1, o, 64);
    }
    if (lane == 0) {
        unsigned int* dst = &ws[(chan * 8 + bg) * 8];
        dst[wave]     = v0;
        dst[wave + 4] = v1;
    }
}

__global__ __launch_bounds__(64) void finalize_k(const unsigned int* __restrict__ ws,
                                                 float* __restrict__ out) {
    const int gid = blockIdx.x * 64 + threadIdx.x;   // 0..767
    if (gid < 768) {
        const int chan = gid >> 3, bin = gid & 7;
        unsigned int s = 0;
        #pragma unroll
        for (int b = 0; b < 8; ++b) s += ws[(chan * 8 + b) * 8 + bin];
        out[gid] = (float)s / 8355840.0f;   // counts / (H*W * 255/8)
    }
}

extern "C" void kernel_launch(void* const* d_in, const int* in_sizes, int n_in,
                              void* d_out, int out_size, void* d_ws, size_t ws_size,
                              hipStream_t stream) {
    const float* x = (const float*)d_in[0];
    unsigned int* wsp = (unsigned int*)d_ws;
    float* out = (float*)d_out;

    dim3 grid(96, 8);
    lbp_main_k<<<grid, 256, 0, stream>>>(x, wsp);
    finalize_k<<<12, 64, 0, stream>>>(wsp, out);
}

// Round 12
// 32.669 us; speedup vs baseline: 1.1953x; 1.1953x over previous
//
#include <hip/hip_runtime.h>

#define W 512
#define H 512
#define CH_PIX (W * H)

// Block: one channel x 4 row-strips (grid 96 x 8; 4 waves/block).
// Wave owns a FULL 512-px row strip of 16 rows; lane owns 8 contiguous px
// (2 x float4); no half-row seam (edges = 2 shuffles + 2 selects per row).
// VGPR discipline (R11 lesson: 132 VGPR = 4 past the 128 cliff -> 2 waves/
// SIMD, 39us): rolling 7-slot buffer (56 regs) in three bursts
// (rows 0-6 / 7-13 / 14-16), natural pressure ~112 < 128 -> 4 waves/SIMD.
// Grid: 768 blocks = 3 blocks/CU x 4 waves = 12 waves/CU < 16 resident ->
// whole dispatch resident in ONE scheduling round, 14 dwordx4/lane in
// flight per burst. NO second __launch_bounds__ arg (R6/R9 spill trap).
// Bottom strip: row 16 zeros -- bit-identical to reference zero padding.
// bin = LBP code >> 5 (== floor(code*8/255)): only bits 5..7 matter:
// s (down), nb5 (down-left bilinear), nb7 (down-right bilinear).
// Per-thread 8x8-bit packed counters in one u64 (max 128/bin), merged once.
__global__ __launch_bounds__(256) void lbp_main_k(const float* __restrict__ x,
                                                  unsigned int* __restrict__ ws) {
    const int chan = blockIdx.x;      // 0..95
    const int bg   = blockIdx.y;      // 0..7
    const int tid  = threadIdx.x;
    const int wave = tid >> 6;
    const int lane = tid & 63;
    const int strip = bg * 4 + wave;  // 0..31
    const int y0 = strip * 16;
    const bool lastStrip = (strip == 31);

    __shared__ unsigned int h[8 * 64];
    for (int i = tid; i < 512; i += 256) h[i] = 0u;
    __syncthreads();

    constexpr double Sd = 0.7071067811865476;
    constexpr double Td = 1.0 - Sd;
    const float wSS = (float)(Sd * Sd);
    const float wST = (float)(Sd * Td);
    const float wTT = (float)(Td * Td);

    const float* rp = x + chan * CH_PIX + y0 * W + (lane << 3);
    const bool l0 = (lane == 0), l63 = (lane == 63);

    unsigned long long c64 = 0ull;

    float4 bufA[7], bufB[7];          // 7 rows x 2 float4 = 56 VGPR

    auto grp = [&](const float c_[4], const float e_[4], const float w_[4],
                   const float s_[4], const float sw_[4], const float se_[4]) {
        #pragma unroll
        for (int i = 0; i < 4; ++i) {
            const float c  = c_[i];
            const float tc = wTT * c;
            const float ts = wST * s_[i];
            const float nb5 = ((wST * w_[i] + tc) + wSS * sw_[i]) + ts;
            const float nb7 = ((tc + wST * e_[i]) + ts) + wSS * se_[i];
            const bool p0 = (nb5   >= c);
            const bool p1 = (s_[i] >= c);
            const bool p2 = (nb7   >= c);
            unsigned int t = p0 ? 0x100u : 1u;     // 1 << (8*p0)
            t = p1 ? (t << 16) : t;                // << 16*p1
            c64 += (unsigned long long)t << (p2 ? 32 : 0);
        }
    };

    auto rowstep = [&](const float4& ma, const float4& mb, float mL, float mR,
                       const float4& da, const float4& db, float dL, float dR) {
        {   // px 0..3
            const float cs[4]  = {ma.x, ma.y, ma.z, ma.w};
            const float es[4]  = {ma.y, ma.z, ma.w, mb.x};
            const float wsA[4] = {mL,   ma.x, ma.y, ma.z};
            const float ss[4]  = {da.x, da.y, da.z, da.w};
            const float sws[4] = {dL,   da.x, da.y, da.z};
            const float ses[4] = {da.y, da.z, da.w, db.x};
            grp(cs, es, wsA, ss, sws, ses);
        }
        {   // px 4..7
            const float cs[4]  = {mb.x, mb.y, mb.z, mb.w};
            const float es[4]  = {mb.y, mb.z, mb.w, mR};
            const float wsA[4] = {ma.w, mb.x, mb.y, mb.z};
            const float ss[4]  = {db.x, db.y, db.z, db.w};
            const float sws[4] = {da.w, db.x, db.y, db.z};
            const float ses[4] = {db.y, db.z, db.w, dR};
            grp(cs, es, wsA, ss, sws, ses);
        }
    };

    auto edges = [&](const float4& a, const float4& b) -> float2 {
        const float up = __shfl_up(b.w, 1, 64);    // lane-1 px7 -> left of px0
        const float dn = __shfl_down(a.x, 1, 64);  // lane+1 px0 -> right of px7
        float2 r;
        r.x = l0  ? 0.0f : up;
        r.y = l63 ? 0.0f : dn;
        return r;
    };

    // ---- burst 1: rows 0..6 ----
    #pragma unroll
    for (int k = 0; k < 7; ++k) {
        bufA[k] = *(const float4*)(rp + k * W);
        bufB[k] = *(const float4*)(rp + k * W + 4);
    }

    // phase 1: rows 0..5 (m = row k, d = slot[k+1])
    float4 ma = bufA[0], mb = bufB[0];
    float2 mlr = edges(ma, mb);
    #pragma unroll
    for (int k = 0; k < 6; ++k) {
        const float4 da = bufA[k + 1], db = bufB[k + 1];
        const float2 dlr = edges(da, db);
        rowstep(ma, mb, mlr.x, mlr.y, da, db, dlr.x, dlr.y);
        ma = da; mb = db; mlr = dlr;
    }

    // ---- burst 2: rows 7..13 into slots 0..6 ----
    #pragma unroll
    for (int k = 0; k < 7; ++k) {
        bufA[k] = *(const float4*)(rp + (7 + k) * W);
        bufB[k] = *(const float4*)(rp + (7 + k) * W + 4);
    }

    // phase 2: rows 6..12 (m carries row 6; d = slot[k] = row 7+k)
    #pragma unroll
    for (int k = 0; k < 7; ++k) {
        const float4 da = bufA[k], db = bufB[k];
        const float2 dlr = edges(da, db);
        rowstep(ma, mb, mlr.x, mlr.y, da, db, dlr.x, dlr.y);
        ma = da; mb = db; mlr = dlr;
    }

    // ---- burst 3: rows 14..16 into slots 0..2 (row 16 zeros on last strip) ----
    #pragma unroll
    for (int k = 0; k < 3; ++k) {
        if (k == 2 && lastStrip) {
            bufA[k] = make_float4(0.0f, 0.0f, 0.0f, 0.0f);
            bufB[k] = make_float4(0.0f, 0.0f, 0.0f, 0.0f);
        } else {
            bufA[k] = *(const float4*)(rp + (14 + k) * W);
            bufB[k] = *(const float4*)(rp + (14 + k) * W + 4);
        }
    }

    // phase 3: rows 13..15 (m carries row 13; d = slot[k] = row 14+k)
    #pragma unroll
    for (int k = 0; k < 3; ++k) {
        const float4 da = bufA[k], db = bufB[k];
        const float2 dlr = edges(da, db);
        rowstep(ma, mb, mlr.x, mlr.y, da, db, dlr.x, dlr.y);
        ma = da; mb = db; mlr = dlr;
    }

    // merge packed byte counters into LDS histogram (8 DS atomics/thread;
    // h[bin*64+lane]: 2 lanes/bank within a wave = conflict-free)
    const unsigned int lo = (unsigned int)c64;
    const unsigned int hi = (unsigned int)(c64 >> 32);
    #pragma unroll
    for (int b = 0; b < 4; ++b) {
        atomicAdd(&h[(b       << 6) + lane], (lo >> (b * 8)) & 0xffu);
        atomicAdd(&h[((b + 4) << 6) + lane], (hi >> (b * 8)) & 0xffu);
    }
    __syncthreads();

    // block tail: wave w reduces bins w and w+4 via shfl_xor tree
    unsigned int v0 = h[tid];          // bin = wave,   copy = lane
    unsigned int v1 = h[tid + 256];    // bin = wave+4, copy = lane
    #pragma unroll
    for (int o = 32; o >= 1; o >>= 1) {
        v0 += __shfl_xor(v0, o, 64);
        v1 += __shfl_xor(v1, o, 64);
    }
    if (lane == 0) {
        unsigned int* dst = &ws[(chan * 8 + bg) * 8];
        dst[wave]     = v0;
        dst[wave + 4] = v1;
    }
}

__global__ __launch_bounds__(64) void finalize_k(const unsigned int* __restrict__ ws,
                                                 float* __restrict__ out) {
    const int gid = blockIdx.x * 64 + threadIdx.x;   // 0..767
    if (gid < 768) {
        const int chan = gid >> 3, bin = gid & 7;
        unsigned int s = 0;
        #pragma unroll
        for (int b = 0; b < 8; ++b) s += ws[(chan * 8 + b) * 8 + bin];
        out[gid] = (float)s / 8355840.0f;   // counts / (H*W * 255/8)
    }
}

extern "C" void kernel_launch(void* const* d_in, const int* in_sizes, int n_in,
                              void* d_out, int out_size, void* d_ws, size_t ws_size,
                              hipStream_t stream) {
    const float* x = (const float*)d_in[0];
    unsigned int* wsp = (unsigned int*)d_ws;
    float* out = (float*)d_out;

    dim3 grid(96, 8);
    lbp_main_k<<<grid, 256, 0, stream>>>(x, wsp);
    finalize_k<<<12, 64, 0, stream>>>(wsp, out);
}

// Round 13
// 30.889 us; speedup vs baseline: 1.2641x; 1.0576x over previous
//
#include <hip/hip_runtime.h>

#define W 512
#define H 512
#define CH_PIX (W * H)

// Lane-edge L/R neighbors via cross-lane shuffle; seam value hk patched at the
// half-row boundary (x=255/256); image edges get 0.
__device__ __forceinline__ float2 lr_for(float4 v, float hk, int half, int lane) {
    const float up = __shfl_up(v.w, 1, 64);    // lane-1's .w  -> left neighbor
    const float dn = __shfl_down(v.x, 1, 64);  // lane+1's .x  -> right neighbor
    const float eL = half ? hk : 0.0f;
    const float eR = half ? 0.0f : hk;
    float2 r;
    r.x = (lane == 0)  ? eL : up;
    r.y = (lane == 63) ? eR : dn;
    return r;
}

// Best-known main kernel (R5/R7 structure, 27.0 us): block = channel x 32-row
// band, 4 waves = 2 row-strips x 2 half-rows, 17-row load burst up front.
// THIS ROUND'S single change: no finalize kernel -- each block atomically
// accumulates its pre-scaled partials (count/8355840 as float) directly into
// d_out; d_out is zeroed by a 3KB hipMemsetAsync before the kernel. Partials
// are exact integer floats (<=16384); 16 atomic adds/cell give <=1e-7 rounding
// noise vs the 2e-4 validation threshold.
// Bottom row (y=511) folded into band 15 (zero "down" row, bit-identical to
// reference zero padding). bin = LBP code >> 5 (== floor(code*8/255)): only
// bits 5..7 matter: s (down), nb5 (down-left bilin), nb7 (down-right bilin).
// NO second __launch_bounds__ arg (R6/R9: cap < natural pressure => spills).
__global__ __launch_bounds__(256) void lbp_main_k(const float* __restrict__ x,
                                                  float* __restrict__ out) {
    const int chan = blockIdx.x;     // 0..95
    const int band = blockIdx.y;     // 0..15
    const int tid  = threadIdx.x;
    const int wave  = tid >> 6;
    const int lane  = tid & 63;
    const int strip = wave >> 1;     // row group
    const int half  = wave & 1;      // x half: 0 -> [0,256), 1 -> [256,512)

    __shared__ unsigned int h[8 * 64];
    for (int i = tid; i < 512; i += 256) h[i] = 0u;
    __syncthreads();

    constexpr double Sd = 0.7071067811865476;
    constexpr double Td = 1.0 - Sd;
    const float wSS = (float)(Sd * Sd);
    const float wST = (float)(Sd * Td);
    const float wTT = (float)(Td * Td);

    const int colbase = half * 256 + (lane << 2);
    const int haloCol = half ? 255 : 256;
    const int cb   = chan * CH_PIX;
    const int y0   = band * 32 + strip * 16;
    const bool lastStrip = (y0 == 496);
    const int base = cb + y0 * W + colbase;

    unsigned long long c64 = 0ull;   // 8 bins x 8-bit counters (max 64/thread)

    // ---- burst: 17 row loads (row 16 of last strip = zeros, no load) ----
    float4 buf[17];
    #pragma unroll
    for (int k = 0; k < 16; ++k) buf[k] = *(const float4*)(x + base + k * W);
    if (lastStrip) {
        buf[16].x = 0.0f; buf[16].y = 0.0f; buf[16].z = 0.0f; buf[16].w = 0.0f;
    } else {
        buf[16] = *(const float4*)(x + base + 16 * W);
    }

    float hvAll = 0.0f;              // 17 seam scalars in lanes 0..16
    {
        int yy = y0 + lane;
        yy = yy > 511 ? 511 : yy;    // lane16 of lastStrip: clamped, unused
        if (lane < 17) hvAll = x[cb + yy * W + haloCol];
    }

    auto rowpix = [&](const float4& m4, float mL, float mR,
                      const float4& d4, float dL, float dR) {
        const float cs[4]  = {m4.x, m4.y, m4.z, m4.w};
        const float es[4]  = {m4.y, m4.z, m4.w, mR};
        const float wsA[4] = {mL,   m4.x, m4.y, m4.z};
        const float ss[4]  = {d4.x, d4.y, d4.z, d4.w};
        const float sws[4] = {dL,   d4.x, d4.y, d4.z};
        const float ses[4] = {d4.y, d4.z, d4.w, dR};
        #pragma unroll
        for (int i = 0; i < 4; ++i) {
            const float c  = cs[i];
            const float tc = wTT * c;
            const float ts = wST * ss[i];
            const float nb5 = ((wST * wsA[i] + tc) + wSS * sws[i]) + ts;
            const float nb7 = ((tc + wST * es[i]) + ts) + wSS * ses[i];
            const bool p0 = (nb5   >= c);
            const bool p1 = (ss[i] >= c);
            const bool p2 = (nb7   >= c);
            unsigned int t = p0 ? 0x100u : 1u;     // 1 << (8*p0)
            t = p1 ? (t << 16) : t;                // << 16*p1
            c64 += (unsigned long long)t << (p2 ? 32 : 0);
        }
    };

    float4 m4  = buf[0];
    float2 mlr = lr_for(m4, __shfl(hvAll, 0, 64), half, lane);

    #pragma unroll
    for (int k = 0; k < 16; ++k) {
        float4 d4 = buf[k + 1];
        float dhk = __shfl(hvAll, k + 1, 64);
        if (k == 15 && lastStrip) {
            d4.x = 0.0f; d4.y = 0.0f; d4.z = 0.0f; d4.w = 0.0f; dhk = 0.0f;
        }
        const float2 dlr = lr_for(d4, dhk, half, lane);
        rowpix(m4, mlr.x, mlr.y, d4, dlr.x, dlr.y);
        m4 = d4; mlr = dlr;
    }

    // merge packed byte counters into LDS histogram (8 DS atomics/thread;
    // h[bin*64+lane]: 2 lanes/bank within a wave = conflict-free)
    const unsigned int lo = (unsigned int)c64;
    const unsigned int hi = (unsigned int)(c64 >> 32);
    #pragma unroll
    for (int b = 0; b < 4; ++b) {
        atomicAdd(&h[(b       << 6) + lane], (lo >> (b * 8)) & 0xffu);
        atomicAdd(&h[((b + 4) << 6) + lane], (hi >> (b * 8)) & 0xffu);
    }
    __syncthreads();

    // block tail: wave w reduces bins w and w+4 via shfl_xor tree, then one
    // pre-scaled float atomic per bin straight into d_out (no finalize pass)
    unsigned int v0 = h[tid];          // bin = wave,   copy = lane
    unsigned int v1 = h[tid + 256];    // bin = wave+4, copy = lane
    #pragma unroll
    for (int o = 32; o >= 1; o >>= 1) {
        v0 += __shfl_xor(v0, o, 64);
        v1 += __shfl_xor(v1, o, 64);
    }
    if (lane == 0) {
        const float inv = 1.0f / 8355840.0f;       // 1 / (H*W * 255/8)
        atomicAdd(&out[chan * 8 + wave],     (float)v0 * inv);
        atomicAdd(&out[chan * 8 + wave + 4], (float)v1 * inv);
    }
}

extern "C" void kernel_launch(void* const* d_in, const int* in_sizes, int n_in,
                              void* d_out, int out_size, void* d_ws, size_t ws_size,
                              hipStream_t stream) {
    const float* x = (const float*)d_in[0];
    float* out = (float*)d_out;

    hipMemsetAsync(out, 0, 768 * sizeof(float), stream);
    dim3 grid(96, 16);
    lbp_main_k<<<grid, 256, 0, stream>>>(x, out);
}